// Round 4
// baseline (2834.540 us; speedup 1.0000x reference)
//
#include <hip/hip_runtime.h>
#include <hip/hip_bf16.h>
#include <math.h>

typedef __hip_bfloat16 bf16;
typedef unsigned short ushort_t;
typedef short bf16x8 __attribute__((ext_vector_type(8)));
typedef float f32x4 __attribute__((ext_vector_type(4)));

// Problem constants
static constexpr int BATCH = 16;
static constexpr int SEQ   = 197;   // NP*NP + 1
static constexpr int NHEAD = 12;
static constexpr int NMLP  = 3072;
static constexpr int NLAYER= 12;
static constexpr int NCLS  = 1000;
static constexpr int NPATCHES = 196;
static constexpr int MPAD  = 3200;  // padded row count for activation buffers

__device__ __forceinline__ ushort_t f2bu(float x) {
    bf16 v = __float2bfloat16(x);
    return *(ushort_t*)&v;
}

// ---------------------------------------------------------------------------
// async global->LDS, 16B per lane
// ---------------------------------------------------------------------------
__device__ __forceinline__ void load_lds16(const void* g, void* l) {
    __builtin_amdgcn_global_load_lds(
        (const __attribute__((address_space(1))) void*)g,
        (__attribute__((address_space(3))) void*)l, 16, 0, 0);
}

// ---------------------------------------------------------------------------
// MFMA GEMM: C[M,N] = op(A[M,K]bf16 @ B[N,K]^T bf16 + bias)
//   mode 0: Cf = v (fp32)
//   mode 1: Cb = bf16(gelu(v))
//   mode 2: Cf += v (fp32 residual accumulate)
// 128x128 tile, BK=64, 4 waves (2x2), 2x(4x4) 16x16x32 MFMAs per wave.
// Double-buffered 2-phase pipeline (compiler-safe __syncthreads form):
//   prologue: stage buf0, sync
//   iter: prefetch buf[cur^1] -> ds_read buf[cur] -> 32 MFMA -> sync
// BK=64 halves the count of latency-exposed barriers vs BK=32 (the round-3
// limiter: ~900cy HBM latency per barrier, compute only ~300cy).
// LDS staging swizzle: row r stores global chunk g (8 shorts) at position
// g^(r&7); achieved with linear LDS dest + pre-swizzled global source
// (global_load_lds requires linear dest). ds_read applies the same XOR.
// XCD swizzle (m204 bijective): by-major chunks per XCD so blocks on one
// XCD L2 share A-panels -> loads hit L2 (~200cy) instead of HBM (~900cy).
// ---------------------------------------------------------------------------
__global__ __launch_bounds__(256) void mfma_gemm(
    const ushort_t* __restrict__ A, const ushort_t* __restrict__ B,
    const float* __restrict__ bias, float* __restrict__ Cf,
    bf16* __restrict__ Cb, int M, int N, int K, int mode)
{
    __shared__ ushort_t As[2][128 * 64];   // 32 KB
    __shared__ ushort_t Bs[2][128 * 64];   // 32 KB

    const int t = threadIdx.x;

    // --- bijective XCD-aware tile swizzle (m204) ---
    const int nbx  = gridDim.x;
    const int nwg  = nbx * gridDim.y;
    const int orig = blockIdx.y * nbx + blockIdx.x;
    const int xcd  = orig & 7;
    const int loc  = orig >> 3;
    const int qq   = nwg >> 3, rr = nwg & 7;
    const int wg   = (xcd < rr ? xcd * (qq + 1) : rr * (qq + 1) + (xcd - rr) * qq) + loc;
    const int m0   = (wg / nbx) * 128;
    const int n0   = (wg % nbx) * 128;

    // --- staging geometry: 8 threads/row, 4 passes of 32 rows ---
    const int srow = t >> 3;                         // 0..31
    const int sw   = ((t & 7) ^ (srow & 7)) * 8;     // pre-swizzled chunk (shorts)

    const int wave = t >> 6;
    const int lane = t & 63;
    const int wm   = (wave >> 1) * 64;
    const int wn   = (wave & 1) * 64;
    const int quad = lane >> 4;
    const int l16  = lane & 15;

    f32x4 acc[4][4] = {};

    const ushort_t* gA[4];
    const ushort_t* gB[4];
    #pragma unroll
    for (int p = 0; p < 4; ++p) {
        gA[p] = A + (size_t)(m0 + p * 32 + srow) * K + sw;
        gB[p] = B + (size_t)(n0 + p * 32 + srow) * K + sw;
    }
    const int t8 = t * 8;

    // prologue: stage first K-tile into buffer 0
    #pragma unroll
    for (int p = 0; p < 4; ++p) {
        load_lds16(gA[p], &As[0][p * 2048 + t8]);
        load_lds16(gB[p], &Bs[0][p * 2048 + t8]);
    }
    __syncthreads();

    int cur = 0;
    for (int k0 = 0; k0 < K; k0 += 64) {
        // prefetch next K-tile into the other buffer (overlaps with compute)
        if (k0 + 64 < K) {
            const int nb = cur ^ 1;
            const int kn = k0 + 64;
            #pragma unroll
            for (int p = 0; p < 4; ++p) {
                load_lds16(gA[p] + kn, &As[nb][p * 2048 + t8]);
                load_lds16(gB[p] + kn, &Bs[nb][p * 2048 + t8]);
            }
        }

        #pragma unroll
        for (int kk = 0; kk < 2; ++kk) {
            bf16x8 af[4], bfr[4];
            const int g = kk * 4 + quad;
            #pragma unroll
            for (int i = 0; i < 4; ++i) {
                int row = wm + i * 16 + l16;
                af[i] = *(const bf16x8*)&As[cur][row * 64 + (g ^ (row & 7)) * 8];
            }
            #pragma unroll
            for (int j = 0; j < 4; ++j) {
                int row = wn + j * 16 + l16;
                bfr[j] = *(const bf16x8*)&Bs[cur][row * 64 + (g ^ (row & 7)) * 8];
            }
            #pragma unroll
            for (int i = 0; i < 4; ++i)
                #pragma unroll
                for (int j = 0; j < 4; ++j)
                    acc[i][j] = __builtin_amdgcn_mfma_f32_16x16x32_bf16(
                        af[i], bfr[j], acc[i][j], 0, 0, 0);
        }

        // drains own prefetch (vmcnt0) + all waves' LDS reads, then barrier
        __syncthreads();
        cur ^= 1;
    }

    #pragma unroll
    for (int i = 0; i < 4; ++i) {
        int mrow = m0 + wm + i * 16 + quad * 4;
        #pragma unroll
        for (int j = 0; j < 4; ++j) {
            int col = n0 + wn + j * 16 + l16;
            float bv = bias ? bias[col] : 0.0f;
            #pragma unroll
            for (int r = 0; r < 4; ++r) {
                int m = mrow + r;
                if (m >= M) continue;
                float v = acc[i][j][r] + bv;
                size_t idx = (size_t)m * N + col;
                if (mode == 1) {
                    v = 0.5f * v * (1.0f + erff(v * 0.70710678118654752f));
                    Cb[idx] = __float2bfloat16(v);
                } else if (mode == 2) {
                    Cf[idx] += v;
                } else {
                    Cf[idx] = v;
                }
            }
        }
    }
}

// ---------------------------------------------------------------------------
// fp32 -> bf16 elementwise
// ---------------------------------------------------------------------------
__global__ void f2b_kernel(const float* __restrict__ src, bf16* __restrict__ dst, int n)
{
    int i4 = (blockIdx.x * 256 + threadIdx.x) * 4;
    for (; i4 < n; i4 += gridDim.x * 1024) {
        float4 v = *(const float4*)(src + i4);
        dst[i4 + 0] = __float2bfloat16(v.x);
        dst[i4 + 1] = __float2bfloat16(v.y);
        dst[i4 + 2] = __float2bfloat16(v.z);
        dst[i4 + 3] = __float2bfloat16(v.w);
    }
}

// ---------------------------------------------------------------------------
// Per-layer weight conversion
// ---------------------------------------------------------------------------
static constexpr int QKV_ELEMS = 3 * 768 * 768;
static constexpr int W1_ELEMS  = 3072 * 768;
static constexpr int CONV_VECS = (QKV_ELEMS + 2 * W1_ELEMS) / 4;
static constexpr int BIAS_VECS = 2304 / 4;

__global__ void convert_layer_kernel(
    const float* __restrict__ Wq, const float* __restrict__ Wk,
    const float* __restrict__ Wv, const float* __restrict__ W1,
    const float* __restrict__ W2, const float* __restrict__ bq,
    const float* __restrict__ bk, const float* __restrict__ bv,
    bf16* __restrict__ wqkv, bf16* __restrict__ w1b, bf16* __restrict__ w2b,
    float* __restrict__ bqkv)
{
    int idx = blockIdx.x * 256 + threadIdx.x;
    if (idx < BIAS_VECS) {
        int j = idx * 4;
        #pragma unroll
        for (int i = 0; i < 4; ++i) {
            int jj = j + i;
            float v = (jj < 768) ? bq[jj] : (jj < 1536) ? bk[jj - 768] : bv[jj - 1536];
            bqkv[jj] = v;
        }
    }
    int w = idx - BIAS_VECS;
    if (w < 0 || w >= CONV_VECS) return;
    const float* src;
    bf16* dst;
    int e;
    if (w < QKV_ELEMS / 4) {
        e = w * 4;
        int tsel = e / (768 * 768);
        int off = e - tsel * 768 * 768;
        src = (tsel == 0 ? Wq : tsel == 1 ? Wk : Wv) + off;
        dst = wqkv + tsel * 768 * 768 + off;
    } else if (w < QKV_ELEMS / 4 + W1_ELEMS / 4) {
        e = (w - QKV_ELEMS / 4) * 4;
        src = W1 + e;
        dst = w1b + e;
    } else {
        e = (w - QKV_ELEMS / 4 - W1_ELEMS / 4) * 4;
        src = W2 + e;
        dst = w2b + e;
    }
    float4 v = *(const float4*)src;
    dst[0] = __float2bfloat16(v.x);
    dst[1] = __float2bfloat16(v.y);
    dst[2] = __float2bfloat16(v.z);
    dst[3] = __float2bfloat16(v.w);
}

// ---------------------------------------------------------------------------
// Patchify
// ---------------------------------------------------------------------------
__global__ void patchify_kernel(const float* __restrict__ images,
                                bf16* __restrict__ patches, int total)
{
    int idx = blockIdx.x * 256 + threadIdx.x;
    if (idx >= total) return;
    int kidx = idx % 768;
    int p = (idx / 768) % NPATCHES;
    int b = idx / (768 * NPATCHES);
    int c  = kidx >> 8;
    int rem = kidx & 255;
    int iy = rem >> 4, ix = rem & 15;
    int py = p / 14, px = p % 14;
    size_t src = (((size_t)(b * 3 + c) * 224) + py * 16 + iy) * 224 + px * 16 + ix;
    patches[idx] = __float2bfloat16(images[src]);
}

// ---------------------------------------------------------------------------
// Assemble residual stream (fp32)
// ---------------------------------------------------------------------------
__global__ void assemble_kernel(const float* __restrict__ tokens,
                                const float* __restrict__ cls,
                                const float* __restrict__ pe,
                                float* __restrict__ out, int total)
{
    int idx = blockIdx.x * 256 + threadIdx.x;
    if (idx >= total) return;
    int d = idx % 768;
    int s = (idx / 768) % SEQ;
    int b = idx / (768 * SEQ);
    float v = (s == 0) ? cls[d]
                       : tokens[((size_t)b * NPATCHES + (s - 1)) * 768 + d];
    out[idx] = v + pe[(size_t)s * 768 + d];
}

// ---------------------------------------------------------------------------
// LayerNorm (768), fp32 in -> bf16 out
// ---------------------------------------------------------------------------
__global__ __launch_bounds__(256) void ln_kernel(const float* __restrict__ inp,
                                                 const float* __restrict__ g,
                                                 const float* __restrict__ beta,
                                                 bf16* __restrict__ xout)
{
    int r = blockIdx.x;
    const float* rowp = inp + (size_t)r * 768;
    float vals[3];
    float s = 0.f, s2 = 0.f;
    #pragma unroll
    for (int i = 0; i < 3; ++i) {
        float v = rowp[threadIdx.x + 256 * i];
        vals[i] = v; s += v; s2 += v * v;
    }
    __shared__ float rs[256], rs2[256];
    rs[threadIdx.x] = s; rs2[threadIdx.x] = s2;
    __syncthreads();
    for (int st = 128; st; st >>= 1) {
        if (threadIdx.x < st) {
            rs[threadIdx.x]  += rs[threadIdx.x + st];
            rs2[threadIdx.x] += rs2[threadIdx.x + st];
        }
        __syncthreads();
    }
    float mean = rs[0] * (1.0f / 768.0f);
    float var  = rs2[0] * (1.0f / 768.0f) - mean * mean;
    float rstd = rsqrtf(var + 1e-5f);
    #pragma unroll
    for (int i = 0; i < 3; ++i) {
        int d = threadIdx.x + 256 * i;
        xout[(size_t)r * 768 + d] =
            __float2bfloat16((vals[i] - mean) * rstd * g[d] + beta[d]);
    }
}

// ---------------------------------------------------------------------------
// MFMA attention: one block per (b,h). qkv fp32 [M,2304] (q|k|v).
// K staged bf16 row-major (stride 72), V^T bf16 (stride 232), t padded to 224.
// Each wave: q-tiles of 16; QK^T -> in-reg softmax -> P via per-wave LDS
// (C-layout -> A-layout) -> PV -> scale 1/l -> += residual out.
// Dynamic LDS: Ks 16128 + Vt 14848 + Ps 4*3712 ushorts = 91648 B.
// ---------------------------------------------------------------------------
static constexpr int ATTN_LDS = (224 * 72 + 64 * 232 + 4 * 16 * 232) * 2;

__global__ __launch_bounds__(256) void attn_mfma_kernel(
    const float* __restrict__ qkv, float* __restrict__ out)
{
    extern __shared__ ushort_t smem[];
    ushort_t* Ks = smem;                  // [224][72]
    ushort_t* Vt = smem + 224 * 72;       // [64][232]
    ushort_t* Ps = Vt + 64 * 232;         // [4][16*232]

    const int bh = blockIdx.x;
    const int b = bh / NHEAD, h = bh % NHEAD;
    const int t = threadIdx.x;
    const int wave = t >> 6, lane = t & 63;
    const int quad = lane >> 4, l16 = lane & 15;

    // --- stage K and V^T (zero-pad rows t >= SEQ) ---
    for (int i = t; i < 224 * 16; i += 256) {
        int tr = i >> 4, e4 = (i & 15) << 2;
        float4 kv = {0.f, 0.f, 0.f, 0.f}, vv = {0.f, 0.f, 0.f, 0.f};
        if (tr < SEQ) {
            const float* base = qkv + (size_t)(b * SEQ + tr) * 2304 + h * 64 + e4;
            kv = *(const float4*)(base + 768);
            vv = *(const float4*)(base + 1536);
        }
        ushort_t kp[4] = {f2bu(kv.x), f2bu(kv.y), f2bu(kv.z), f2bu(kv.w)};
        *(uint2*)&Ks[tr * 72 + e4] = *(const uint2*)kp;
        Vt[(e4 + 0) * 232 + tr] = f2bu(vv.x);
        Vt[(e4 + 1) * 232 + tr] = f2bu(vv.y);
        Vt[(e4 + 2) * 232 + tr] = f2bu(vv.z);
        Vt[(e4 + 3) * 232 + tr] = f2bu(vv.w);
    }
    __syncthreads();

    bf16* pw = (bf16*)(Ps + wave * 16 * 232);

    for (int qt = wave; qt < 13; qt += 4) {
        const int q0 = qt * 16;

        // Q A-fragments (2 k-chunks of 32) straight from global
        bf16x8 qf[2];
        #pragma unroll
        for (int c = 0; c < 2; ++c) {
            const float* qp = qkv + (size_t)(b * SEQ + q0 + l16) * 2304
                            + h * 64 + c * 32 + quad * 8;
            float4 a = *(const float4*)qp;
            float4 b2 = *(const float4*)(qp + 4);
            qf[c][0] = (short)f2bu(a.x);  qf[c][1] = (short)f2bu(a.y);
            qf[c][2] = (short)f2bu(a.z);  qf[c][3] = (short)f2bu(a.w);
            qf[c][4] = (short)f2bu(b2.x); qf[c][5] = (short)f2bu(b2.y);
            qf[c][6] = (short)f2bu(b2.z); qf[c][7] = (short)f2bu(b2.w);
        }

        // S = Q K^T over 14 t-tiles
        f32x4 sc[14] = {};
        #pragma unroll
        for (int tt = 0; tt < 14; ++tt) {
            #pragma unroll
            for (int c = 0; c < 2; ++c) {
                bf16x8 kf = *(const bf16x8*)&Ks[(tt * 16 + l16) * 72 + c * 32 + quad * 8];
                sc[tt] = __builtin_amdgcn_mfma_f32_16x16x32_bf16(qf[c], kf, sc[tt], 0, 0, 0);
            }
        }

        // scale + mask, row max
        f32x4 m4;
        #pragma unroll
        for (int r = 0; r < 4; ++r) m4[r] = -3.4e38f;
        #pragma unroll
        for (int tt = 0; tt < 14; ++tt) {
            int tg = tt * 16 + l16;
            #pragma unroll
            for (int r = 0; r < 4; ++r) {
                sc[tt][r] = (tg < SEQ) ? sc[tt][r] * 0.125f : -1e30f;
                m4[r] = fmaxf(m4[r], sc[tt][r]);
            }
        }
        #pragma unroll
        for (int off = 1; off < 16; off <<= 1)
            #pragma unroll
            for (int r = 0; r < 4; ++r)
                m4[r] = fmaxf(m4[r], __shfl_xor(m4[r], off));

        // exp + row sum
        f32x4 l4 = {};
        #pragma unroll
        for (int tt = 0; tt < 14; ++tt)
            #pragma unroll
            for (int r = 0; r < 4; ++r) {
                float p = __expf(sc[tt][r] - m4[r]);
                sc[tt][r] = p;
                l4[r] += p;
            }
        #pragma unroll
        for (int off = 1; off < 16; off <<= 1)
            #pragma unroll
            for (int r = 0; r < 4; ++r)
                l4[r] += __shfl_xor(l4[r], off);

        // P (C-layout) -> per-wave LDS (A-layout source)
        #pragma unroll
        for (int tt = 0; tt < 14; ++tt)
            #pragma unroll
            for (int r = 0; r < 4; ++r)
                pw[(quad * 4 + r) * 232 + tt * 16 + l16] = __float2bfloat16(sc[tt][r]);

        // O = P V  (7 k-chunks of 32, 4 e-tiles of 16)
        f32x4 oa[4] = {};
        #pragma unroll
        for (int c = 0; c < 7; ++c) {
            bf16x8 pf = *(const bf16x8*)&((ushort_t*)pw)[l16 * 232 + c * 32 + quad * 8];
            #pragma unroll
            for (int nt = 0; nt < 4; ++nt) {
                bf16x8 vf = *(const bf16x8*)&Vt[(nt * 16 + l16) * 232 + c * 32 + quad * 8];
                oa[nt] = __builtin_amdgcn_mfma_f32_16x16x32_bf16(pf, vf, oa[nt], 0, 0, 0);
            }
        }

        // accumulate into residual
        #pragma unroll
        for (int r = 0; r < 4; ++r) {
            int q = q0 + quad * 4 + r;
            if (q >= SEQ) continue;
            float rl = 1.0f / l4[r];
            float* orow = out + (size_t)(b * SEQ + q) * 768 + h * 64;
            #pragma unroll
            for (int nt = 0; nt < 4; ++nt)
                orow[nt * 16 + l16] += oa[nt][r] * rl;
        }
    }
}

// ---------------------------------------------------------------------------
// Classifier stage 1: logits[b,j] = pooled(b) . Wc[j] + bc[j]
// grid (4, BATCH), 256 threads
// ---------------------------------------------------------------------------
__global__ __launch_bounds__(256) void cls_logits_kernel(
    const float* __restrict__ out, const float* __restrict__ Wc,
    const float* __restrict__ bc, float* __restrict__ logits)
{
    int b = blockIdx.y;
    int j = blockIdx.x * 256 + threadIdx.x;
    __shared__ float pooled[768];
    for (int d = threadIdx.x; d < 768; d += 256)
        pooled[d] = out[(size_t)b * SEQ * 768 + d];
    __syncthreads();
    if (j >= NCLS) return;
    const float* wr = Wc + (size_t)j * 768;
    float acc = 0.f;
    for (int d = 0; d < 768; ++d) acc += pooled[d] * wr[d];
    logits[b * NCLS + j] = acc + bc[j];
}

// ---------------------------------------------------------------------------
// Classifier stage 2: softmax over 1000 logits per batch row
// ---------------------------------------------------------------------------
__global__ __launch_bounds__(256) void cls_softmax_kernel(
    const float* __restrict__ logits, float* __restrict__ dout)
{
    int b = blockIdx.x;
    __shared__ float red[256];
    const float* lg = logits + b * NCLS;

    float m = -3.4e38f;
    for (int j = threadIdx.x; j < NCLS; j += 256) m = fmaxf(m, lg[j]);
    red[threadIdx.x] = m; __syncthreads();
    for (int st = 128; st; st >>= 1) {
        if (threadIdx.x < st) red[threadIdx.x] = fmaxf(red[threadIdx.x], red[threadIdx.x + st]);
        __syncthreads();
    }
    m = red[0]; __syncthreads();

    float ssum = 0.f;
    for (int j = threadIdx.x; j < NCLS; j += 256) ssum += __expf(lg[j] - m);
    red[threadIdx.x] = ssum; __syncthreads();
    for (int st = 128; st; st >>= 1) {
        if (threadIdx.x < st) red[threadIdx.x] += red[threadIdx.x + st];
        __syncthreads();
    }
    float inv = 1.0f / red[0];
    __syncthreads();

    for (int j = threadIdx.x; j < NCLS; j += 256)
        dout[(size_t)b * NCLS + j] = __expf(lg[j] - m) * inv;
}

// ---------------------------------------------------------------------------
extern "C" void kernel_launch(void* const* d_in, const int* in_sizes, int n_in,
                              void* d_out, int out_size, void* d_ws, size_t ws_size,
                              hipStream_t stream)
{
    const float* images  = (const float*)d_in[0];
    const float* Wm      = (const float*)d_in[1];
    const float* bm      = (const float*)d_in[2];
    const float* cls_tok = (const float*)d_in[3];
    const float* pe      = (const float*)d_in[4];
    const float* g1      = (const float*)d_in[5];
    const float* beta1   = (const float*)d_in[6];
    const float* Wq      = (const float*)d_in[7];
    const float* bq      = (const float*)d_in[8];
    const float* Wk      = (const float*)d_in[9];
    const float* bk      = (const float*)d_in[10];
    const float* Wv      = (const float*)d_in[11];
    const float* bv      = (const float*)d_in[12];
    const float* g2      = (const float*)d_in[13];
    const float* beta2   = (const float*)d_in[14];
    const float* W1      = (const float*)d_in[15];
    const float* b1      = (const float*)d_in[16];
    const float* W2      = (const float*)d_in[17];
    const float* b2      = (const float*)d_in[18];
    const float* Wc      = (const float*)d_in[19];
    const float* bc      = (const float*)d_in[20];
    float* outp = (float*)d_out;

    const int M  = BATCH * SEQ;           // 3152
    const int MP = BATCH * NPATCHES;      // 3136

    char* ws = (char*)d_ws;
    float* out  = (float*)ws; ws += (size_t)MPAD * 768 * 4;
    bf16*  xb   = (bf16*) ws; ws += (size_t)MPAD * 768 * 2;
    float* qkv  = (float*)ws; ws += (size_t)MPAD * 2304 * 4;
    bf16*  h    = (bf16*) ws; ws += (size_t)MPAD * 3072 * 2;
    bf16*  wqkv = (bf16*) ws; ws += (size_t)2304 * 768 * 2;
    bf16*  w1b  = (bf16*) ws; ws += (size_t)3072 * 768 * 2;
    bf16*  w2b  = (bf16*) ws; ws += (size_t)768 * 3072 * 2;
    float* bqkv = (float*)ws; ws += 2304 * 4;
    bf16*  wmb  = (bf16*) ws; ws += (size_t)768 * 768 * 2;
    float* logits = (float*)ws; ws += (size_t)BATCH * NCLS * 4;
    // overlays inside h (unused until first MLP1)
    bf16*  patches = (bf16*)h;
    float* tokens  = (float*)((char*)h + (size_t)MPAD * 768 * 2);

    hipFuncSetAttribute((const void*)attn_mfma_kernel,
                        hipFuncAttributeMaxDynamicSharedMemorySize, ATTN_LDS);

    // --- patch embedding ---
    f2b_kernel<<<576, 256, 0, stream>>>(Wm, wmb, 768 * 768);
    int tot_p = MP * 768;
    patchify_kernel<<<(tot_p + 255) / 256, 256, 0, stream>>>(images, patches, tot_p);
    mfma_gemm<<<dim3(768 / 128, (MP + 127) / 128), 256, 0, stream>>>(
        (const ushort_t*)patches, (const ushort_t*)wmb, bm, tokens, nullptr,
        MP, 768, 768, 0);
    int tot_a = M * 768;
    assemble_kernel<<<(tot_a + 255) / 256, 256, 0, stream>>>(tokens, cls_tok, pe, out, tot_a);

    const int MB = (M + 127) / 128;  // 25
    const int conv_blocks = (CONV_VECS + BIAS_VECS + 255) / 256;

    for (int l = 0; l < NLAYER; ++l) {
        convert_layer_kernel<<<conv_blocks, 256, 0, stream>>>(
            Wq + (size_t)l * 768 * 768, Wk + (size_t)l * 768 * 768,
            Wv + (size_t)l * 768 * 768, W1 + (size_t)l * NMLP * 768,
            W2 + (size_t)l * 768 * NMLP, bq + l * 768, bk + l * 768, bv + l * 768,
            wqkv, w1b, w2b, bqkv);

        ln_kernel<<<M, 256, 0, stream>>>(out, g1 + l * 768, beta1 + l * 768, xb);
        mfma_gemm<<<dim3(2304 / 128, MB), 256, 0, stream>>>(
            (const ushort_t*)xb, (const ushort_t*)wqkv, bqkv, qkv, nullptr,
            M, 2304, 768, 0);
        attn_mfma_kernel<<<BATCH * NHEAD, 256, ATTN_LDS, stream>>>(qkv, out);
        ln_kernel<<<M, 256, 0, stream>>>(out, g2 + l * 768, beta2 + l * 768, xb);
        mfma_gemm<<<dim3(NMLP / 128, MB), 256, 0, stream>>>(
            (const ushort_t*)xb, (const ushort_t*)w1b, b1 + l * NMLP, nullptr, h,
            M, NMLP, 768, 1);
        mfma_gemm<<<dim3(768 / 128, MB), 256, 0, stream>>>(
            (const ushort_t*)h, (const ushort_t*)w2b, b2 + l * 768, out, nullptr,
            M, 768, NMLP, 2);
    }

    cls_logits_kernel<<<dim3(4, BATCH), 256, 0, stream>>>(out, Wc, bc, logits);
    cls_softmax_kernel<<<BATCH, 256, 0, stream>>>(logits, outp);
}

// Round 5
// 2634.333 us; speedup vs baseline: 1.0760x; 1.0760x over previous
//
#include <hip/hip_runtime.h>
#include <hip/hip_bf16.h>
#include <math.h>

typedef __hip_bfloat16 bf16;
typedef unsigned short ushort_t;
typedef short bf16x8 __attribute__((ext_vector_type(8)));
typedef float f32x4 __attribute__((ext_vector_type(4)));

// Problem constants
static constexpr int BATCH = 16;
static constexpr int SEQ   = 197;   // NP*NP + 1
static constexpr int NHEAD = 12;
static constexpr int NMLP  = 3072;
static constexpr int NLAYER= 12;
static constexpr int NCLS  = 1000;
static constexpr int NPATCHES = 196;
static constexpr int MPAD  = 3200;  // padded row count for activation buffers

__device__ __forceinline__ ushort_t f2bu(float x) {
    bf16 v = __float2bfloat16(x);
    return *(ushort_t*)&v;
}

// ---------------------------------------------------------------------------
// async global->LDS, 16B per lane
// ---------------------------------------------------------------------------
__device__ __forceinline__ void load_lds16(const void* g, void* l) {
    __builtin_amdgcn_global_load_lds(
        (const __attribute__((address_space(1))) void*)g,
        (__attribute__((address_space(3))) void*)l, 16, 0, 0);
}

// ---------------------------------------------------------------------------
// MFMA GEMM: C[M,N] = op(A[M,K]bf16 @ B[N,K]^T bf16 + bias)
//   mode 0: Cf = v (fp32);  mode 1: Cb = bf16(gelu(v));  mode 2: Cf += v
// 128x128 tile, 4 waves (2x2), 16x16x32 MFMAs, double-buffered 2-phase
// pipeline (prefetch next K-tile before computing current; __syncthreads
// per iteration = compiler-safe vmcnt(0)+barrier).
//
// BK policy (measured r3/r4): block-count-dependent.
//   BK=32 (LDS 32KB): high-block-count GEMMs (QKV 450, MLP1 600 blocks) —
//     small LDS lets 2-3 blocks co-reside per CU and hide each other's
//     HBM latency. BK=64 here regressed MLP1 91->103.6us (r4).
//   BK=64+XCD swizzle (LDS 64KB): low-block-count GEMMs (patch/MLP2, 150
//     blocks, 1 block/CU) — no co-resident partner exists, so halving the
//     number of latency-exposed barriers is the only lever.
// ---------------------------------------------------------------------------
template<int BK, bool SWZ>
__global__ __launch_bounds__(256) void mfma_gemm(
    const ushort_t* __restrict__ A, const ushort_t* __restrict__ B,
    const float* __restrict__ bias, float* __restrict__ Cf,
    bf16* __restrict__ Cb, int M, int N, int K, int mode)
{
    __shared__ ushort_t As[2][128 * BK];
    __shared__ ushort_t Bs[2][128 * BK];

    const int t = threadIdx.x;

    int m0, n0;
    if constexpr (SWZ) {
        // bijective XCD-aware tile swizzle (m204)
        const int nbx  = gridDim.x;
        const int nwg  = nbx * gridDim.y;
        const int orig = blockIdx.y * nbx + blockIdx.x;
        const int xcd  = orig & 7;
        const int loc  = orig >> 3;
        const int qq   = nwg >> 3, rr = nwg & 7;
        const int wg   = (xcd < rr ? xcd * (qq + 1) : rr * (qq + 1) + (xcd - rr) * qq) + loc;
        m0 = (wg / nbx) * 128;
        n0 = (wg % nbx) * 128;
    } else {
        m0 = blockIdx.y * 128;
        n0 = blockIdx.x * 128;
    }

    const int wave = t >> 6;
    const int lane = t & 63;
    const int wm   = (wave >> 1) * 64;
    const int wn   = (wave & 1) * 64;
    const int quad = lane >> 4;
    const int l16  = lane & 15;

    f32x4 acc[4][4] = {};
    const int t8 = t * 8;

    if constexpr (BK == 32) {
        // ---- round-3 verified path ----
        const int srow = t >> 2;                       // 0..63
        const int sp   = (t & 3) ^ ((srow >> 1) & 3);  // swizzled k-part
        const int skp  = sp * 8;

        const ushort_t* gA0 = A + (size_t)(m0 + srow) * K + skp;
        const ushort_t* gA1 = A + (size_t)(m0 + 64 + srow) * K + ((t & 3) ^ (((srow + 64) >> 1) & 3)) * 8;
        const ushort_t* gB0 = B + (size_t)(n0 + srow) * K + skp;
        const ushort_t* gB1 = B + (size_t)(n0 + 64 + srow) * K + ((t & 3) ^ (((srow + 64) >> 1) & 3)) * 8;

        load_lds16(gA0, &As[0][t8]);
        load_lds16(gA1, &As[0][t8 + 2048]);
        load_lds16(gB0, &Bs[0][t8]);
        load_lds16(gB1, &Bs[0][t8 + 2048]);
        __syncthreads();

        int cur = 0;
        for (int k0 = 0; k0 < K; k0 += 32) {
            if (k0 + 32 < K) {
                const int nb = cur ^ 1;
                const int kn = k0 + 32;
                load_lds16(gA0 + kn, &As[nb][t8]);
                load_lds16(gA1 + kn, &As[nb][t8 + 2048]);
                load_lds16(gB0 + kn, &Bs[nb][t8]);
                load_lds16(gB1 + kn, &Bs[nb][t8 + 2048]);
            }
            bf16x8 af[4], bfr[4];
            #pragma unroll
            for (int i = 0; i < 4; ++i) {
                int row = wm + i * 16 + l16;
                int s = quad ^ ((row >> 1) & 3);
                af[i] = *(const bf16x8*)&As[cur][row * 32 + s * 8];
            }
            #pragma unroll
            for (int j = 0; j < 4; ++j) {
                int row = wn + j * 16 + l16;
                int s = quad ^ ((row >> 1) & 3);
                bfr[j] = *(const bf16x8*)&Bs[cur][row * 32 + s * 8];
            }
            #pragma unroll
            for (int i = 0; i < 4; ++i)
                #pragma unroll
                for (int j = 0; j < 4; ++j)
                    acc[i][j] = __builtin_amdgcn_mfma_f32_16x16x32_bf16(
                        af[i], bfr[j], acc[i][j], 0, 0, 0);
            __syncthreads();
            cur ^= 1;
        }
    } else {
        // ---- round-4 verified path (BK=64) ----
        const int srow = t >> 3;                         // 0..31
        const int sw   = ((t & 7) ^ (srow & 7)) * 8;     // pre-swizzled chunk

        const ushort_t* gA[4];
        const ushort_t* gB[4];
        #pragma unroll
        for (int p = 0; p < 4; ++p) {
            gA[p] = A + (size_t)(m0 + p * 32 + srow) * K + sw;
            gB[p] = B + (size_t)(n0 + p * 32 + srow) * K + sw;
        }

        #pragma unroll
        for (int p = 0; p < 4; ++p) {
            load_lds16(gA[p], &As[0][p * 2048 + t8]);
            load_lds16(gB[p], &Bs[0][p * 2048 + t8]);
        }
        __syncthreads();

        int cur = 0;
        for (int k0 = 0; k0 < K; k0 += 64) {
            if (k0 + 64 < K) {
                const int nb = cur ^ 1;
                const int kn = k0 + 64;
                #pragma unroll
                for (int p = 0; p < 4; ++p) {
                    load_lds16(gA[p] + kn, &As[nb][p * 2048 + t8]);
                    load_lds16(gB[p] + kn, &Bs[nb][p * 2048 + t8]);
                }
            }
            #pragma unroll
            for (int kk = 0; kk < 2; ++kk) {
                bf16x8 af[4], bfr[4];
                const int g = kk * 4 + quad;
                #pragma unroll
                for (int i = 0; i < 4; ++i) {
                    int row = wm + i * 16 + l16;
                    af[i] = *(const bf16x8*)&As[cur][row * 64 + (g ^ (row & 7)) * 8];
                }
                #pragma unroll
                for (int j = 0; j < 4; ++j) {
                    int row = wn + j * 16 + l16;
                    bfr[j] = *(const bf16x8*)&Bs[cur][row * 64 + (g ^ (row & 7)) * 8];
                }
                #pragma unroll
                for (int i = 0; i < 4; ++i)
                    #pragma unroll
                    for (int j = 0; j < 4; ++j)
                        acc[i][j] = __builtin_amdgcn_mfma_f32_16x16x32_bf16(
                            af[i], bfr[j], acc[i][j], 0, 0, 0);
            }
            __syncthreads();
            cur ^= 1;
        }
    }

    #pragma unroll
    for (int i = 0; i < 4; ++i) {
        int mrow = m0 + wm + i * 16 + quad * 4;
        #pragma unroll
        for (int j = 0; j < 4; ++j) {
            int col = n0 + wn + j * 16 + l16;
            float bv = bias ? bias[col] : 0.0f;
            #pragma unroll
            for (int r = 0; r < 4; ++r) {
                int m = mrow + r;
                if (m >= M) continue;
                float v = acc[i][j][r] + bv;
                size_t idx = (size_t)m * N + col;
                if (mode == 1) {
                    v = 0.5f * v * (1.0f + erff(v * 0.70710678118654752f));
                    Cb[idx] = __float2bfloat16(v);
                } else if (mode == 2) {
                    Cf[idx] += v;
                } else {
                    Cf[idx] = v;
                }
            }
        }
    }
}

// ---------------------------------------------------------------------------
// fp32 -> bf16 elementwise
// ---------------------------------------------------------------------------
__global__ void f2b_kernel(const float* __restrict__ src, bf16* __restrict__ dst, int n)
{
    int i4 = (blockIdx.x * 256 + threadIdx.x) * 4;
    for (; i4 < n; i4 += gridDim.x * 1024) {
        float4 v = *(const float4*)(src + i4);
        dst[i4 + 0] = __float2bfloat16(v.x);
        dst[i4 + 1] = __float2bfloat16(v.y);
        dst[i4 + 2] = __float2bfloat16(v.z);
        dst[i4 + 3] = __float2bfloat16(v.w);
    }
}

// ---------------------------------------------------------------------------
// Per-layer weight conversion
// ---------------------------------------------------------------------------
static constexpr int QKV_ELEMS = 3 * 768 * 768;
static constexpr int W1_ELEMS  = 3072 * 768;
static constexpr int CONV_VECS = (QKV_ELEMS + 2 * W1_ELEMS) / 4;
static constexpr int BIAS_VECS = 2304 / 4;

__global__ void convert_layer_kernel(
    const float* __restrict__ Wq, const float* __restrict__ Wk,
    const float* __restrict__ Wv, const float* __restrict__ W1,
    const float* __restrict__ W2, const float* __restrict__ bq,
    const float* __restrict__ bk, const float* __restrict__ bv,
    bf16* __restrict__ wqkv, bf16* __restrict__ w1b, bf16* __restrict__ w2b,
    float* __restrict__ bqkv)
{
    int idx = blockIdx.x * 256 + threadIdx.x;
    if (idx < BIAS_VECS) {
        int j = idx * 4;
        #pragma unroll
        for (int i = 0; i < 4; ++i) {
            int jj = j + i;
            float v = (jj < 768) ? bq[jj] : (jj < 1536) ? bk[jj - 768] : bv[jj - 1536];
            bqkv[jj] = v;
        }
    }
    int w = idx - BIAS_VECS;
    if (w < 0 || w >= CONV_VECS) return;
    const float* src;
    bf16* dst;
    int e;
    if (w < QKV_ELEMS / 4) {
        e = w * 4;
        int tsel = e / (768 * 768);
        int off = e - tsel * 768 * 768;
        src = (tsel == 0 ? Wq : tsel == 1 ? Wk : Wv) + off;
        dst = wqkv + tsel * 768 * 768 + off;
    } else if (w < QKV_ELEMS / 4 + W1_ELEMS / 4) {
        e = (w - QKV_ELEMS / 4) * 4;
        src = W1 + e;
        dst = w1b + e;
    } else {
        e = (w - QKV_ELEMS / 4 - W1_ELEMS / 4) * 4;
        src = W2 + e;
        dst = w2b + e;
    }
    float4 v = *(const float4*)src;
    dst[0] = __float2bfloat16(v.x);
    dst[1] = __float2bfloat16(v.y);
    dst[2] = __float2bfloat16(v.z);
    dst[3] = __float2bfloat16(v.w);
}

// ---------------------------------------------------------------------------
// Patchify
// ---------------------------------------------------------------------------
__global__ void patchify_kernel(const float* __restrict__ images,
                                bf16* __restrict__ patches, int total)
{
    int idx = blockIdx.x * 256 + threadIdx.x;
    if (idx >= total) return;
    int kidx = idx % 768;
    int p = (idx / 768) % NPATCHES;
    int b = idx / (768 * NPATCHES);
    int c  = kidx >> 8;
    int rem = kidx & 255;
    int iy = rem >> 4, ix = rem & 15;
    int py = p / 14, px = p % 14;
    size_t src = (((size_t)(b * 3 + c) * 224) + py * 16 + iy) * 224 + px * 16 + ix;
    patches[idx] = __float2bfloat16(images[src]);
}

// ---------------------------------------------------------------------------
// Assemble residual stream (fp32)
// ---------------------------------------------------------------------------
__global__ void assemble_kernel(const float* __restrict__ tokens,
                                const float* __restrict__ cls,
                                const float* __restrict__ pe,
                                float* __restrict__ out, int total)
{
    int idx = blockIdx.x * 256 + threadIdx.x;
    if (idx >= total) return;
    int d = idx % 768;
    int s = (idx / 768) % SEQ;
    int b = idx / (768 * SEQ);
    float v = (s == 0) ? cls[d]
                       : tokens[((size_t)b * NPATCHES + (s - 1)) * 768 + d];
    out[idx] = v + pe[(size_t)s * 768 + d];
}

// ---------------------------------------------------------------------------
// LayerNorm (768), fp32 in -> bf16 out
// ---------------------------------------------------------------------------
__global__ __launch_bounds__(256) void ln_kernel(const float* __restrict__ inp,
                                                 const float* __restrict__ g,
                                                 const float* __restrict__ beta,
                                                 bf16* __restrict__ xout)
{
    int r = blockIdx.x;
    const float* rowp = inp + (size_t)r * 768;
    float vals[3];
    float s = 0.f, s2 = 0.f;
    #pragma unroll
    for (int i = 0; i < 3; ++i) {
        float v = rowp[threadIdx.x + 256 * i];
        vals[i] = v; s += v; s2 += v * v;
    }
    __shared__ float rs[256], rs2[256];
    rs[threadIdx.x] = s; rs2[threadIdx.x] = s2;
    __syncthreads();
    for (int st = 128; st; st >>= 1) {
        if (threadIdx.x < st) {
            rs[threadIdx.x]  += rs[threadIdx.x + st];
            rs2[threadIdx.x] += rs2[threadIdx.x + st];
        }
        __syncthreads();
    }
    float mean = rs[0] * (1.0f / 768.0f);
    float var  = rs2[0] * (1.0f / 768.0f) - mean * mean;
    float rstd = rsqrtf(var + 1e-5f);
    #pragma unroll
    for (int i = 0; i < 3; ++i) {
        int d = threadIdx.x + 256 * i;
        xout[(size_t)r * 768 + d] =
            __float2bfloat16((vals[i] - mean) * rstd * g[d] + beta[d]);
    }
}

// ---------------------------------------------------------------------------
// MFMA attention: one block per (b,h). qkv fp32 [M,2304] (q|k|v).
// ---------------------------------------------------------------------------
static constexpr int ATTN_LDS = (224 * 72 + 64 * 232 + 4 * 16 * 232) * 2;

__global__ __launch_bounds__(256) void attn_mfma_kernel(
    const float* __restrict__ qkv, float* __restrict__ out)
{
    extern __shared__ ushort_t smem[];
    ushort_t* Ks = smem;                  // [224][72]
    ushort_t* Vt = smem + 224 * 72;       // [64][232]
    ushort_t* Ps = Vt + 64 * 232;         // [4][16*232]

    const int bh = blockIdx.x;
    const int b = bh / NHEAD, h = bh % NHEAD;
    const int t = threadIdx.x;
    const int wave = t >> 6, lane = t & 63;
    const int quad = lane >> 4, l16 = lane & 15;

    // --- stage K and V^T (zero-pad rows t >= SEQ) ---
    for (int i = t; i < 224 * 16; i += 256) {
        int tr = i >> 4, e4 = (i & 15) << 2;
        float4 kv = {0.f, 0.f, 0.f, 0.f}, vv = {0.f, 0.f, 0.f, 0.f};
        if (tr < SEQ) {
            const float* base = qkv + (size_t)(b * SEQ + tr) * 2304 + h * 64 + e4;
            kv = *(const float4*)(base + 768);
            vv = *(const float4*)(base + 1536);
        }
        ushort_t kp[4] = {f2bu(kv.x), f2bu(kv.y), f2bu(kv.z), f2bu(kv.w)};
        *(uint2*)&Ks[tr * 72 + e4] = *(const uint2*)kp;
        Vt[(e4 + 0) * 232 + tr] = f2bu(vv.x);
        Vt[(e4 + 1) * 232 + tr] = f2bu(vv.y);
        Vt[(e4 + 2) * 232 + tr] = f2bu(vv.z);
        Vt[(e4 + 3) * 232 + tr] = f2bu(vv.w);
    }
    __syncthreads();

    bf16* pw = (bf16*)(Ps + wave * 16 * 232);

    for (int qt = wave; qt < 13; qt += 4) {
        const int q0 = qt * 16;

        bf16x8 qf[2];
        #pragma unroll
        for (int c = 0; c < 2; ++c) {
            const float* qp = qkv + (size_t)(b * SEQ + q0 + l16) * 2304
                            + h * 64 + c * 32 + quad * 8;
            float4 a = *(const float4*)qp;
            float4 b2 = *(const float4*)(qp + 4);
            qf[c][0] = (short)f2bu(a.x);  qf[c][1] = (short)f2bu(a.y);
            qf[c][2] = (short)f2bu(a.z);  qf[c][3] = (short)f2bu(a.w);
            qf[c][4] = (short)f2bu(b2.x); qf[c][5] = (short)f2bu(b2.y);
            qf[c][6] = (short)f2bu(b2.z); qf[c][7] = (short)f2bu(b2.w);
        }

        f32x4 sc[14] = {};
        #pragma unroll
        for (int tt = 0; tt < 14; ++tt) {
            #pragma unroll
            for (int c = 0; c < 2; ++c) {
                bf16x8 kf = *(const bf16x8*)&Ks[(tt * 16 + l16) * 72 + c * 32 + quad * 8];
                sc[tt] = __builtin_amdgcn_mfma_f32_16x16x32_bf16(qf[c], kf, sc[tt], 0, 0, 0);
            }
        }

        f32x4 m4;
        #pragma unroll
        for (int r = 0; r < 4; ++r) m4[r] = -3.4e38f;
        #pragma unroll
        for (int tt = 0; tt < 14; ++tt) {
            int tg = tt * 16 + l16;
            #pragma unroll
            for (int r = 0; r < 4; ++r) {
                sc[tt][r] = (tg < SEQ) ? sc[tt][r] * 0.125f : -1e30f;
                m4[r] = fmaxf(m4[r], sc[tt][r]);
            }
        }
        #pragma unroll
        for (int off = 1; off < 16; off <<= 1)
            #pragma unroll
            for (int r = 0; r < 4; ++r)
                m4[r] = fmaxf(m4[r], __shfl_xor(m4[r], off));

        f32x4 l4 = {};
        #pragma unroll
        for (int tt = 0; tt < 14; ++tt)
            #pragma unroll
            for (int r = 0; r < 4; ++r) {
                float p = __expf(sc[tt][r] - m4[r]);
                sc[tt][r] = p;
                l4[r] += p;
            }
        #pragma unroll
        for (int off = 1; off < 16; off <<= 1)
            #pragma unroll
            for (int r = 0; r < 4; ++r)
                l4[r] += __shfl_xor(l4[r], off);

        #pragma unroll
        for (int tt = 0; tt < 14; ++tt)
            #pragma unroll
            for (int r = 0; r < 4; ++r)
                pw[(quad * 4 + r) * 232 + tt * 16 + l16] = __float2bfloat16(sc[tt][r]);

        f32x4 oa[4] = {};
        #pragma unroll
        for (int c = 0; c < 7; ++c) {
            bf16x8 pf = *(const bf16x8*)&((ushort_t*)pw)[l16 * 232 + c * 32 + quad * 8];
            #pragma unroll
            for (int nt = 0; nt < 4; ++nt) {
                bf16x8 vf = *(const bf16x8*)&Vt[(nt * 16 + l16) * 232 + c * 32 + quad * 8];
                oa[nt] = __builtin_amdgcn_mfma_f32_16x16x32_bf16(pf, vf, oa[nt], 0, 0, 0);
            }
        }

        #pragma unroll
        for (int r = 0; r < 4; ++r) {
            int q = q0 + quad * 4 + r;
            if (q >= SEQ) continue;
            float rl = 1.0f / l4[r];
            float* orow = out + (size_t)(b * SEQ + q) * 768 + h * 64;
            #pragma unroll
            for (int nt = 0; nt < 4; ++nt)
                orow[nt * 16 + l16] += oa[nt][r] * rl;
        }
    }
}

// ---------------------------------------------------------------------------
// Classifier stage 1: logits[b,j] = pooled(b) . Wc[j] + bc[j]
// ---------------------------------------------------------------------------
__global__ __launch_bounds__(256) void cls_logits_kernel(
    const float* __restrict__ out, const float* __restrict__ Wc,
    const float* __restrict__ bc, float* __restrict__ logits)
{
    int b = blockIdx.y;
    int j = blockIdx.x * 256 + threadIdx.x;
    __shared__ float pooled[768];
    for (int d = threadIdx.x; d < 768; d += 256)
        pooled[d] = out[(size_t)b * SEQ * 768 + d];
    __syncthreads();
    if (j >= NCLS) return;
    const float* wr = Wc + (size_t)j * 768;
    float acc = 0.f;
    for (int d = 0; d < 768; ++d) acc += pooled[d] * wr[d];
    logits[b * NCLS + j] = acc + bc[j];
}

// ---------------------------------------------------------------------------
// Classifier stage 2: softmax over 1000 logits per batch row
// ---------------------------------------------------------------------------
__global__ __launch_bounds__(256) void cls_softmax_kernel(
    const float* __restrict__ logits, float* __restrict__ dout)
{
    int b = blockIdx.x;
    __shared__ float red[256];
    const float* lg = logits + b * NCLS;

    float m = -3.4e38f;
    for (int j = threadIdx.x; j < NCLS; j += 256) m = fmaxf(m, lg[j]);
    red[threadIdx.x] = m; __syncthreads();
    for (int st = 128; st; st >>= 1) {
        if (threadIdx.x < st) red[threadIdx.x] = fmaxf(red[threadIdx.x], red[threadIdx.x + st]);
        __syncthreads();
    }
    m = red[0]; __syncthreads();

    float ssum = 0.f;
    for (int j = threadIdx.x; j < NCLS; j += 256) ssum += __expf(lg[j] - m);
    red[threadIdx.x] = ssum; __syncthreads();
    for (int st = 128; st; st >>= 1) {
        if (threadIdx.x < st) red[threadIdx.x] += red[threadIdx.x + st];
        __syncthreads();
    }
    float inv = 1.0f / red[0];
    __syncthreads();

    for (int j = threadIdx.x; j < NCLS; j += 256)
        dout[(size_t)b * NCLS + j] = __expf(lg[j] - m) * inv;
}

// ---------------------------------------------------------------------------
extern "C" void kernel_launch(void* const* d_in, const int* in_sizes, int n_in,
                              void* d_out, int out_size, void* d_ws, size_t ws_size,
                              hipStream_t stream)
{
    const float* images  = (const float*)d_in[0];
    const float* Wm      = (const float*)d_in[1];
    const float* bm      = (const float*)d_in[2];
    const float* cls_tok = (const float*)d_in[3];
    const float* pe      = (const float*)d_in[4];
    const float* g1      = (const float*)d_in[5];
    const float* beta1   = (const float*)d_in[6];
    const float* Wq      = (const float*)d_in[7];
    const float* bq      = (const float*)d_in[8];
    const float* Wk      = (const float*)d_in[9];
    const float* bk      = (const float*)d_in[10];
    const float* Wv      = (const float*)d_in[11];
    const float* bv      = (const float*)d_in[12];
    const float* g2      = (const float*)d_in[13];
    const float* beta2   = (const float*)d_in[14];
    const float* W1      = (const float*)d_in[15];
    const float* b1      = (const float*)d_in[16];
    const float* W2      = (const float*)d_in[17];
    const float* b2      = (const float*)d_in[18];
    const float* Wc      = (const float*)d_in[19];
    const float* bc      = (const float*)d_in[20];
    float* outp = (float*)d_out;

    const int M  = BATCH * SEQ;           // 3152
    const int MP = BATCH * NPATCHES;      // 3136

    char* ws = (char*)d_ws;
    float* out  = (float*)ws; ws += (size_t)MPAD * 768 * 4;
    bf16*  xb   = (bf16*) ws; ws += (size_t)MPAD * 768 * 2;
    float* qkv  = (float*)ws; ws += (size_t)MPAD * 2304 * 4;
    bf16*  h    = (bf16*) ws; ws += (size_t)MPAD * 3072 * 2;
    bf16*  wqkv = (bf16*) ws; ws += (size_t)2304 * 768 * 2;
    bf16*  w1b  = (bf16*) ws; ws += (size_t)3072 * 768 * 2;
    bf16*  w2b  = (bf16*) ws; ws += (size_t)768 * 3072 * 2;
    float* bqkv = (float*)ws; ws += 2304 * 4;
    bf16*  wmb  = (bf16*) ws; ws += (size_t)768 * 768 * 2;
    float* logits = (float*)ws; ws += (size_t)BATCH * NCLS * 4;
    // overlays inside h (unused until first MLP1)
    bf16*  patches = (bf16*)h;
    float* tokens  = (float*)((char*)h + (size_t)MPAD * 768 * 2);

    hipFuncSetAttribute((const void*)attn_mfma_kernel,
                        hipFuncAttributeMaxDynamicSharedMemorySize, ATTN_LDS);

    // --- patch embedding ---
    f2b_kernel<<<576, 256, 0, stream>>>(Wm, wmb, 768 * 768);
    int tot_p = MP * 768;
    patchify_kernel<<<(tot_p + 255) / 256, 256, 0, stream>>>(images, patches, tot_p);
    mfma_gemm<64, true><<<dim3(768 / 128, (MP + 127) / 128), 256, 0, stream>>>(
        (const ushort_t*)patches, (const ushort_t*)wmb, bm, tokens, nullptr,
        MP, 768, 768, 0);
    int tot_a = M * 768;
    assemble_kernel<<<(tot_a + 255) / 256, 256, 0, stream>>>(tokens, cls_tok, pe, out, tot_a);

    const int MB = (M + 127) / 128;  // 25
    const int conv_blocks = (CONV_VECS + BIAS_VECS + 255) / 256;

    for (int l = 0; l < NLAYER; ++l) {
        convert_layer_kernel<<<conv_blocks, 256, 0, stream>>>(
            Wq + (size_t)l * 768 * 768, Wk + (size_t)l * 768 * 768,
            Wv + (size_t)l * 768 * 768, W1 + (size_t)l * NMLP * 768,
            W2 + (size_t)l * 768 * NMLP, bq + l * 768, bk + l * 768, bv + l * 768,
            wqkv, w1b, w2b, bqkv);

        ln_kernel<<<M, 256, 0, stream>>>(out, g1 + l * 768, beta1 + l * 768, xb);
        // QKV: 450 blocks -> BK=32 (co-resident blocks hide latency)
        mfma_gemm<32, false><<<dim3(2304 / 128, MB), 256, 0, stream>>>(
            (const ushort_t*)xb, (const ushort_t*)wqkv, bqkv, qkv, nullptr,
            M, 2304, 768, 0);
        attn_mfma_kernel<<<BATCH * NHEAD, 256, ATTN_LDS, stream>>>(qkv, out);
        ln_kernel<<<M, 256, 0, stream>>>(out, g2 + l * 768, beta2 + l * 768, xb);
        // MLP1: 600 blocks -> BK=32
        mfma_gemm<32, false><<<dim3(NMLP / 128, MB), 256, 0, stream>>>(
            (const ushort_t*)xb, (const ushort_t*)w1b, b1 + l * NMLP, nullptr, h,
            M, NMLP, 768, 1);
        // MLP2: 150 blocks (1/CU) -> BK=64 + XCD swizzle
        mfma_gemm<64, true><<<dim3(768 / 128, MB), 256, 0, stream>>>(
            (const ushort_t*)h, (const ushort_t*)w2b, b2 + l * 768, out, nullptr,
            M, 768, NMLP, 2);
    }

    cls_logits_kernel<<<dim3(4, BATCH), 256, 0, stream>>>(out, Wc, bc, logits);
    cls_softmax_kernel<<<BATCH, 256, 0, stream>>>(logits, outp);
}

// Round 6
// 2257.076 us; speedup vs baseline: 1.2558x; 1.1671x over previous
//
#include <hip/hip_runtime.h>
#include <hip/hip_bf16.h>
#include <math.h>

typedef __hip_bfloat16 bf16;
typedef unsigned short ushort_t;
typedef short bf16x8 __attribute__((ext_vector_type(8)));
typedef float f32x4 __attribute__((ext_vector_type(4)));

// Problem constants
static constexpr int BATCH = 16;
static constexpr int SEQ   = 197;   // NP*NP + 1
static constexpr int NHEAD = 12;
static constexpr int NMLP  = 3072;
static constexpr int NLAYER= 12;
static constexpr int NCLS  = 1000;
static constexpr int NPATCHES = 196;
static constexpr int MPAD  = 3200;  // padded row count for activation buffers

__device__ __forceinline__ ushort_t f2bu(float x) {
    bf16 v = __float2bfloat16(x);
    return *(ushort_t*)&v;
}

// ---------------------------------------------------------------------------
// async global->LDS, 16B per lane
// ---------------------------------------------------------------------------
__device__ __forceinline__ void load_lds16(const void* g, void* l) {
    __builtin_amdgcn_global_load_lds(
        (const __attribute__((address_space(1))) void*)g,
        (__attribute__((address_space(3))) void*)l, 16, 0, 0);
}

// ---------------------------------------------------------------------------
// MFMA GEMM: C[M,N] = op(A[M,K]bf16 @ B[N,K]^T bf16 + bias)
//   mode 0: Cf = v (fp32);  mode 1: Cb = bf16(gelu(v));  mode 2: Cf += v
// With gridDim.z > 1 (deterministic split-K): each z-slice computes K-range
// [z*K/gz, (z+1)*K/gz) and stores RAW partial sums (no bias/act) to
// Cf + z*M*N; a separate reduce4_kernel combines them. No atomics.
//
// 128x128 tile, 4 waves (2x2), 16x16x32 MFMAs, double-buffered 2-phase
// pipeline. BK policy (measured r3/r4/r5): block-count-dependent.
//   BK=32: high-block-count GEMMs (QKV 450, MLP1 600) — co-resident blocks
//     hide latency; BK=64 regressed MLP1 (r4).
//   BK=64 + XCD swizzle: low-block-count GEMMs — r5: MLP2 91.7->82us,
//     FETCH 71.8->35MB. Split-K (this round) pushes MLP2 to 600 blocks,
//     the regime where MLP1 shows ~5x better per-iteration efficiency.
// ---------------------------------------------------------------------------
template<int BK, bool SWZ>
__global__ __launch_bounds__(256) void mfma_gemm(
    const ushort_t* __restrict__ A, const ushort_t* __restrict__ B,
    const float* __restrict__ bias, float* __restrict__ Cf,
    bf16* __restrict__ Cb, int M, int N, int K, int mode)
{
    __shared__ ushort_t As[2][128 * BK];
    __shared__ ushort_t Bs[2][128 * BK];

    const int t = threadIdx.x;

    int m0, n0;
    if constexpr (SWZ) {
        // bijective XCD-aware tile swizzle (m204), per z-slice.
        // (z offsets rotate the actual XCD id by a constant per slice, which
        // preserves the co-location property.)
        const int nbx  = gridDim.x;
        const int nwg  = nbx * gridDim.y;
        const int orig = blockIdx.y * nbx + blockIdx.x;
        const int xcd  = orig & 7;
        const int loc  = orig >> 3;
        const int qq   = nwg >> 3, rr = nwg & 7;
        const int wg   = (xcd < rr ? xcd * (qq + 1) : rr * (qq + 1) + (xcd - rr) * qq) + loc;
        m0 = (wg / nbx) * 128;
        n0 = (wg % nbx) * 128;
    } else {
        m0 = blockIdx.y * 128;
        n0 = blockIdx.x * 128;
    }

    // split-K slice
    const int ksp = K / (int)gridDim.z;          // K per slice
    const int kb  = blockIdx.z * ksp;            // this slice's K offset

    const int wave = t >> 6;
    const int lane = t & 63;
    const int wm   = (wave >> 1) * 64;
    const int wn   = (wave & 1) * 64;
    const int quad = lane >> 4;
    const int l16  = lane & 15;

    f32x4 acc[4][4] = {};
    const int t8 = t * 8;

    if constexpr (BK == 32) {
        // ---- round-3 verified path ----
        const int srow = t >> 2;                       // 0..63
        const int sp   = (t & 3) ^ ((srow >> 1) & 3);  // swizzled k-part
        const int skp  = sp * 8;

        const ushort_t* gA0 = A + (size_t)(m0 + srow) * K + skp + kb;
        const ushort_t* gA1 = A + (size_t)(m0 + 64 + srow) * K + ((t & 3) ^ (((srow + 64) >> 1) & 3)) * 8 + kb;
        const ushort_t* gB0 = B + (size_t)(n0 + srow) * K + skp + kb;
        const ushort_t* gB1 = B + (size_t)(n0 + 64 + srow) * K + ((t & 3) ^ (((srow + 64) >> 1) & 3)) * 8 + kb;

        load_lds16(gA0, &As[0][t8]);
        load_lds16(gA1, &As[0][t8 + 2048]);
        load_lds16(gB0, &Bs[0][t8]);
        load_lds16(gB1, &Bs[0][t8 + 2048]);
        __syncthreads();

        int cur = 0;
        for (int k0 = 0; k0 < ksp; k0 += 32) {
            if (k0 + 32 < ksp) {
                const int nb = cur ^ 1;
                const int kn = k0 + 32;
                load_lds16(gA0 + kn, &As[nb][t8]);
                load_lds16(gA1 + kn, &As[nb][t8 + 2048]);
                load_lds16(gB0 + kn, &Bs[nb][t8]);
                load_lds16(gB1 + kn, &Bs[nb][t8 + 2048]);
            }
            bf16x8 af[4], bfr[4];
            #pragma unroll
            for (int i = 0; i < 4; ++i) {
                int row = wm + i * 16 + l16;
                int s = quad ^ ((row >> 1) & 3);
                af[i] = *(const bf16x8*)&As[cur][row * 32 + s * 8];
            }
            #pragma unroll
            for (int j = 0; j < 4; ++j) {
                int row = wn + j * 16 + l16;
                int s = quad ^ ((row >> 1) & 3);
                bfr[j] = *(const bf16x8*)&Bs[cur][row * 32 + s * 8];
            }
            #pragma unroll
            for (int i = 0; i < 4; ++i)
                #pragma unroll
                for (int j = 0; j < 4; ++j)
                    acc[i][j] = __builtin_amdgcn_mfma_f32_16x16x32_bf16(
                        af[i], bfr[j], acc[i][j], 0, 0, 0);
            __syncthreads();
            cur ^= 1;
        }
    } else {
        // ---- round-4/5 verified path (BK=64) ----
        const int srow = t >> 3;                         // 0..31
        const int sw   = ((t & 7) ^ (srow & 7)) * 8;     // pre-swizzled chunk

        const ushort_t* gA[4];
        const ushort_t* gB[4];
        #pragma unroll
        for (int p = 0; p < 4; ++p) {
            gA[p] = A + (size_t)(m0 + p * 32 + srow) * K + sw + kb;
            gB[p] = B + (size_t)(n0 + p * 32 + srow) * K + sw + kb;
        }

        #pragma unroll
        for (int p = 0; p < 4; ++p) {
            load_lds16(gA[p], &As[0][p * 2048 + t8]);
            load_lds16(gB[p], &Bs[0][p * 2048 + t8]);
        }
        __syncthreads();

        int cur = 0;
        for (int k0 = 0; k0 < ksp; k0 += 64) {
            if (k0 + 64 < ksp) {
                const int nb = cur ^ 1;
                const int kn = k0 + 64;
                #pragma unroll
                for (int p = 0; p < 4; ++p) {
                    load_lds16(gA[p] + kn, &As[nb][p * 2048 + t8]);
                    load_lds16(gB[p] + kn, &Bs[nb][p * 2048 + t8]);
                }
            }
            #pragma unroll
            for (int kk = 0; kk < 2; ++kk) {
                bf16x8 af[4], bfr[4];
                const int g = kk * 4 + quad;
                #pragma unroll
                for (int i = 0; i < 4; ++i) {
                    int row = wm + i * 16 + l16;
                    af[i] = *(const bf16x8*)&As[cur][row * 64 + (g ^ (row & 7)) * 8];
                }
                #pragma unroll
                for (int j = 0; j < 4; ++j) {
                    int row = wn + j * 16 + l16;
                    bfr[j] = *(const bf16x8*)&Bs[cur][row * 64 + (g ^ (row & 7)) * 8];
                }
                #pragma unroll
                for (int i = 0; i < 4; ++i)
                    #pragma unroll
                    for (int j = 0; j < 4; ++j)
                        acc[i][j] = __builtin_amdgcn_mfma_f32_16x16x32_bf16(
                            af[i], bfr[j], acc[i][j], 0, 0, 0);
            }
            __syncthreads();
            cur ^= 1;
        }
    }

    if (gridDim.z > 1) {
        // raw partial store (deterministic split-K); bias/act in reduce4
        float* dst = Cf + (size_t)blockIdx.z * M * N;
        #pragma unroll
        for (int i = 0; i < 4; ++i) {
            int mrow = m0 + wm + i * 16 + quad * 4;
            #pragma unroll
            for (int j = 0; j < 4; ++j) {
                int col = n0 + wn + j * 16 + l16;
                #pragma unroll
                for (int r = 0; r < 4; ++r) {
                    int m = mrow + r;
                    if (m >= M) continue;
                    dst[(size_t)m * N + col] = acc[i][j][r];
                }
            }
        }
        return;
    }

    #pragma unroll
    for (int i = 0; i < 4; ++i) {
        int mrow = m0 + wm + i * 16 + quad * 4;
        #pragma unroll
        for (int j = 0; j < 4; ++j) {
            int col = n0 + wn + j * 16 + l16;
            float bv = bias ? bias[col] : 0.0f;
            #pragma unroll
            for (int r = 0; r < 4; ++r) {
                int m = mrow + r;
                if (m >= M) continue;
                float v = acc[i][j][r] + bv;
                size_t idx = (size_t)m * N + col;
                if (mode == 1) {
                    v = 0.5f * v * (1.0f + erff(v * 0.70710678118654752f));
                    Cb[idx] = __float2bfloat16(v);
                } else if (mode == 2) {
                    Cf[idx] += v;
                } else {
                    Cf[idx] = v;
                }
            }
        }
    }
}

// ---------------------------------------------------------------------------
// Combine 4 split-K partials + bias.  mode 0: dst = s;  mode 2: dst += s.
// ---------------------------------------------------------------------------
__global__ __launch_bounds__(256) void reduce4_kernel(
    const float* __restrict__ parts, const float* __restrict__ bias,
    float* __restrict__ dst, int total, int N, int mode, size_t slice)
{
    int i = (blockIdx.x * 256 + threadIdx.x) * 4;
    for (; i < total; i += gridDim.x * 1024) {
        float4 v0 = *(const float4*)(parts + i);
        float4 v1 = *(const float4*)(parts + slice + i);
        float4 v2 = *(const float4*)(parts + 2 * slice + i);
        float4 v3 = *(const float4*)(parts + 3 * slice + i);
        float4 bv = *(const float4*)(bias + (i % N));
        float4 s;
        s.x = v0.x + v1.x + v2.x + v3.x + bv.x;
        s.y = v0.y + v1.y + v2.y + v3.y + bv.y;
        s.z = v0.z + v1.z + v2.z + v3.z + bv.z;
        s.w = v0.w + v1.w + v2.w + v3.w + bv.w;
        if (mode == 2) {
            float4 o = *(const float4*)(dst + i);
            s.x += o.x; s.y += o.y; s.z += o.z; s.w += o.w;
        }
        *(float4*)(dst + i) = s;
    }
}

// ---------------------------------------------------------------------------
// fp32 -> bf16 elementwise
// ---------------------------------------------------------------------------
__global__ void f2b_kernel(const float* __restrict__ src, bf16* __restrict__ dst, int n)
{
    int i4 = (blockIdx.x * 256 + threadIdx.x) * 4;
    for (; i4 < n; i4 += gridDim.x * 1024) {
        float4 v = *(const float4*)(src + i4);
        dst[i4 + 0] = __float2bfloat16(v.x);
        dst[i4 + 1] = __float2bfloat16(v.y);
        dst[i4 + 2] = __float2bfloat16(v.z);
        dst[i4 + 3] = __float2bfloat16(v.w);
    }
}

// ---------------------------------------------------------------------------
// Per-layer weight conversion
// ---------------------------------------------------------------------------
static constexpr int QKV_ELEMS = 3 * 768 * 768;
static constexpr int W1_ELEMS  = 3072 * 768;
static constexpr int CONV_VECS = (QKV_ELEMS + 2 * W1_ELEMS) / 4;
static constexpr int BIAS_VECS = 2304 / 4;

__global__ void convert_layer_kernel(
    const float* __restrict__ Wq, const float* __restrict__ Wk,
    const float* __restrict__ Wv, const float* __restrict__ W1,
    const float* __restrict__ W2, const float* __restrict__ bq,
    const float* __restrict__ bk, const float* __restrict__ bv,
    bf16* __restrict__ wqkv, bf16* __restrict__ w1b, bf16* __restrict__ w2b,
    float* __restrict__ bqkv)
{
    int idx = blockIdx.x * 256 + threadIdx.x;
    if (idx < BIAS_VECS) {
        int j = idx * 4;
        #pragma unroll
        for (int i = 0; i < 4; ++i) {
            int jj = j + i;
            float v = (jj < 768) ? bq[jj] : (jj < 1536) ? bk[jj - 768] : bv[jj - 1536];
            bqkv[jj] = v;
        }
    }
    int w = idx - BIAS_VECS;
    if (w < 0 || w >= CONV_VECS) return;
    const float* src;
    bf16* dst;
    int e;
    if (w < QKV_ELEMS / 4) {
        e = w * 4;
        int tsel = e / (768 * 768);
        int off = e - tsel * 768 * 768;
        src = (tsel == 0 ? Wq : tsel == 1 ? Wk : Wv) + off;
        dst = wqkv + tsel * 768 * 768 + off;
    } else if (w < QKV_ELEMS / 4 + W1_ELEMS / 4) {
        e = (w - QKV_ELEMS / 4) * 4;
        src = W1 + e;
        dst = w1b + e;
    } else {
        e = (w - QKV_ELEMS / 4 - W1_ELEMS / 4) * 4;
        src = W2 + e;
        dst = w2b + e;
    }
    float4 v = *(const float4*)src;
    dst[0] = __float2bfloat16(v.x);
    dst[1] = __float2bfloat16(v.y);
    dst[2] = __float2bfloat16(v.z);
    dst[3] = __float2bfloat16(v.w);
}

// ---------------------------------------------------------------------------
// Patchify
// ---------------------------------------------------------------------------
__global__ void patchify_kernel(const float* __restrict__ images,
                                bf16* __restrict__ patches, int total)
{
    int idx = blockIdx.x * 256 + threadIdx.x;
    if (idx >= total) return;
    int kidx = idx % 768;
    int p = (idx / 768) % NPATCHES;
    int b = idx / (768 * NPATCHES);
    int c  = kidx >> 8;
    int rem = kidx & 255;
    int iy = rem >> 4, ix = rem & 15;
    int py = p / 14, px = p % 14;
    size_t src = (((size_t)(b * 3 + c) * 224) + py * 16 + iy) * 224 + px * 16 + ix;
    patches[idx] = __float2bfloat16(images[src]);
}

// ---------------------------------------------------------------------------
// Assemble residual stream (fp32)
// ---------------------------------------------------------------------------
__global__ void assemble_kernel(const float* __restrict__ tokens,
                                const float* __restrict__ cls,
                                const float* __restrict__ pe,
                                float* __restrict__ out, int total)
{
    int idx = blockIdx.x * 256 + threadIdx.x;
    if (idx >= total) return;
    int d = idx % 768;
    int s = (idx / 768) % SEQ;
    int b = idx / (768 * SEQ);
    float v = (s == 0) ? cls[d]
                       : tokens[((size_t)b * NPATCHES + (s - 1)) * 768 + d];
    out[idx] = v + pe[(size_t)s * 768 + d];
}

// ---------------------------------------------------------------------------
// LayerNorm (768), fp32 in -> bf16 out
// ---------------------------------------------------------------------------
__global__ __launch_bounds__(256) void ln_kernel(const float* __restrict__ inp,
                                                 const float* __restrict__ g,
                                                 const float* __restrict__ beta,
                                                 bf16* __restrict__ xout)
{
    int r = blockIdx.x;
    const float* rowp = inp + (size_t)r * 768;
    float vals[3];
    float s = 0.f, s2 = 0.f;
    #pragma unroll
    for (int i = 0; i < 3; ++i) {
        float v = rowp[threadIdx.x + 256 * i];
        vals[i] = v; s += v; s2 += v * v;
    }
    __shared__ float rs[256], rs2[256];
    rs[threadIdx.x] = s; rs2[threadIdx.x] = s2;
    __syncthreads();
    for (int st = 128; st; st >>= 1) {
        if (threadIdx.x < st) {
            rs[threadIdx.x]  += rs[threadIdx.x + st];
            rs2[threadIdx.x] += rs2[threadIdx.x + st];
        }
        __syncthreads();
    }
    float mean = rs[0] * (1.0f / 768.0f);
    float var  = rs2[0] * (1.0f / 768.0f) - mean * mean;
    float rstd = rsqrtf(var + 1e-5f);
    #pragma unroll
    for (int i = 0; i < 3; ++i) {
        int d = threadIdx.x + 256 * i;
        xout[(size_t)r * 768 + d] =
            __float2bfloat16((vals[i] - mean) * rstd * g[d] + beta[d]);
    }
}

// ---------------------------------------------------------------------------
// MFMA attention: one block per (b,h). qkv fp32 [M,2304] (q|k|v).
// ---------------------------------------------------------------------------
static constexpr int ATTN_LDS = (224 * 72 + 64 * 232 + 4 * 16 * 232) * 2;

__global__ __launch_bounds__(256) void attn_mfma_kernel(
    const float* __restrict__ qkv, float* __restrict__ out)
{
    extern __shared__ ushort_t smem[];
    ushort_t* Ks = smem;                  // [224][72]
    ushort_t* Vt = smem + 224 * 72;       // [64][232]
    ushort_t* Ps = Vt + 64 * 232;         // [4][16*232]

    const int bh = blockIdx.x;
    const int b = bh / NHEAD, h = bh % NHEAD;
    const int t = threadIdx.x;
    const int wave = t >> 6, lane = t & 63;
    const int quad = lane >> 4, l16 = lane & 15;

    // --- stage K and V^T (zero-pad rows t >= SEQ) ---
    for (int i = t; i < 224 * 16; i += 256) {
        int tr = i >> 4, e4 = (i & 15) << 2;
        float4 kv = {0.f, 0.f, 0.f, 0.f}, vv = {0.f, 0.f, 0.f, 0.f};
        if (tr < SEQ) {
            const float* base = qkv + (size_t)(b * SEQ + tr) * 2304 + h * 64 + e4;
            kv = *(const float4*)(base + 768);
            vv = *(const float4*)(base + 1536);
        }
        ushort_t kp[4] = {f2bu(kv.x), f2bu(kv.y), f2bu(kv.z), f2bu(kv.w)};
        *(uint2*)&Ks[tr * 72 + e4] = *(const uint2*)kp;
        Vt[(e4 + 0) * 232 + tr] = f2bu(vv.x);
        Vt[(e4 + 1) * 232 + tr] = f2bu(vv.y);
        Vt[(e4 + 2) * 232 + tr] = f2bu(vv.z);
        Vt[(e4 + 3) * 232 + tr] = f2bu(vv.w);
    }
    __syncthreads();

    bf16* pw = (bf16*)(Ps + wave * 16 * 232);

    for (int qt = wave; qt < 13; qt += 4) {
        const int q0 = qt * 16;

        bf16x8 qf[2];
        #pragma unroll
        for (int c = 0; c < 2; ++c) {
            const float* qp = qkv + (size_t)(b * SEQ + q0 + l16) * 2304
                            + h * 64 + c * 32 + quad * 8;
            float4 a = *(const float4*)qp;
            float4 b2 = *(const float4*)(qp + 4);
            qf[c][0] = (short)f2bu(a.x);  qf[c][1] = (short)f2bu(a.y);
            qf[c][2] = (short)f2bu(a.z);  qf[c][3] = (short)f2bu(a.w);
            qf[c][4] = (short)f2bu(b2.x); qf[c][5] = (short)f2bu(b2.y);
            qf[c][6] = (short)f2bu(b2.z); qf[c][7] = (short)f2bu(b2.w);
        }

        f32x4 sc[14] = {};
        #pragma unroll
        for (int tt = 0; tt < 14; ++tt) {
            #pragma unroll
            for (int c = 0; c < 2; ++c) {
                bf16x8 kf = *(const bf16x8*)&Ks[(tt * 16 + l16) * 72 + c * 32 + quad * 8];
                sc[tt] = __builtin_amdgcn_mfma_f32_16x16x32_bf16(qf[c], kf, sc[tt], 0, 0, 0);
            }
        }

        f32x4 m4;
        #pragma unroll
        for (int r = 0; r < 4; ++r) m4[r] = -3.4e38f;
        #pragma unroll
        for (int tt = 0; tt < 14; ++tt) {
            int tg = tt * 16 + l16;
            #pragma unroll
            for (int r = 0; r < 4; ++r) {
                sc[tt][r] = (tg < SEQ) ? sc[tt][r] * 0.125f : -1e30f;
                m4[r] = fmaxf(m4[r], sc[tt][r]);
            }
        }
        #pragma unroll
        for (int off = 1; off < 16; off <<= 1)
            #pragma unroll
            for (int r = 0; r < 4; ++r)
                m4[r] = fmaxf(m4[r], __shfl_xor(m4[r], off));

        f32x4 l4 = {};
        #pragma unroll
        for (int tt = 0; tt < 14; ++tt)
            #pragma unroll
            for (int r = 0; r < 4; ++r) {
                float p = __expf(sc[tt][r] - m4[r]);
                sc[tt][r] = p;
                l4[r] += p;
            }
        #pragma unroll
        for (int off = 1; off < 16; off <<= 1)
            #pragma unroll
            for (int r = 0; r < 4; ++r)
                l4[r] += __shfl_xor(l4[r], off);

        #pragma unroll
        for (int tt = 0; tt < 14; ++tt)
            #pragma unroll
            for (int r = 0; r < 4; ++r)
                pw[(quad * 4 + r) * 232 + tt * 16 + l16] = __float2bfloat16(sc[tt][r]);

        f32x4 oa[4] = {};
        #pragma unroll
        for (int c = 0; c < 7; ++c) {
            bf16x8 pf = *(const bf16x8*)&((ushort_t*)pw)[l16 * 232 + c * 32 + quad * 8];
            #pragma unroll
            for (int nt = 0; nt < 4; ++nt) {
                bf16x8 vf = *(const bf16x8*)&Vt[(nt * 16 + l16) * 232 + c * 32 + quad * 8];
                oa[nt] = __builtin_amdgcn_mfma_f32_16x16x32_bf16(pf, vf, oa[nt], 0, 0, 0);
            }
        }

        #pragma unroll
        for (int r = 0; r < 4; ++r) {
            int q = q0 + quad * 4 + r;
            if (q >= SEQ) continue;
            float rl = 1.0f / l4[r];
            float* orow = out + (size_t)(b * SEQ + q) * 768 + h * 64;
            #pragma unroll
            for (int nt = 0; nt < 4; ++nt)
                orow[nt * 16 + l16] += oa[nt][r] * rl;
        }
    }
}

// ---------------------------------------------------------------------------
// Classifier stage 1: logits[b,j] = pooled(b) . Wc[j] + bc[j]
// ---------------------------------------------------------------------------
__global__ __launch_bounds__(256) void cls_logits_kernel(
    const float* __restrict__ out, const float* __restrict__ Wc,
    const float* __restrict__ bc, float* __restrict__ logits)
{
    int b = blockIdx.y;
    int j = blockIdx.x * 256 + threadIdx.x;
    __shared__ float pooled[768];
    for (int d = threadIdx.x; d < 768; d += 256)
        pooled[d] = out[(size_t)b * SEQ * 768 + d];
    __syncthreads();
    if (j >= NCLS) return;
    const float* wr = Wc + (size_t)j * 768;
    float acc = 0.f;
    for (int d = 0; d < 768; ++d) acc += pooled[d] * wr[d];
    logits[b * NCLS + j] = acc + bc[j];
}

// ---------------------------------------------------------------------------
// Classifier stage 2: softmax over 1000 logits per batch row
// ---------------------------------------------------------------------------
__global__ __launch_bounds__(256) void cls_softmax_kernel(
    const float* __restrict__ logits, float* __restrict__ dout)
{
    int b = blockIdx.x;
    __shared__ float red[256];
    const float* lg = logits + b * NCLS;

    float m = -3.4e38f;
    for (int j = threadIdx.x; j < NCLS; j += 256) m = fmaxf(m, lg[j]);
    red[threadIdx.x] = m; __syncthreads();
    for (int st = 128; st; st >>= 1) {
        if (threadIdx.x < st) red[threadIdx.x] = fmaxf(red[threadIdx.x], red[threadIdx.x + st]);
        __syncthreads();
    }
    m = red[0]; __syncthreads();

    float ssum = 0.f;
    for (int j = threadIdx.x; j < NCLS; j += 256) ssum += __expf(lg[j] - m);
    red[threadIdx.x] = ssum; __syncthreads();
    for (int st = 128; st; st >>= 1) {
        if (threadIdx.x < st) red[threadIdx.x] += red[threadIdx.x + st];
        __syncthreads();
    }
    float inv = 1.0f / red[0];
    __syncthreads();

    for (int j = threadIdx.x; j < NCLS; j += 256)
        dout[(size_t)b * NCLS + j] = __expf(lg[j] - m) * inv;
}

// ---------------------------------------------------------------------------
extern "C" void kernel_launch(void* const* d_in, const int* in_sizes, int n_in,
                              void* d_out, int out_size, void* d_ws, size_t ws_size,
                              hipStream_t stream)
{
    const float* images  = (const float*)d_in[0];
    const float* Wm      = (const float*)d_in[1];
    const float* bm      = (const float*)d_in[2];
    const float* cls_tok = (const float*)d_in[3];
    const float* pe      = (const float*)d_in[4];
    const float* g1      = (const float*)d_in[5];
    const float* beta1   = (const float*)d_in[6];
    const float* Wq      = (const float*)d_in[7];
    const float* bq      = (const float*)d_in[8];
    const float* Wk      = (const float*)d_in[9];
    const float* bk      = (const float*)d_in[10];
    const float* Wv      = (const float*)d_in[11];
    const float* bv      = (const float*)d_in[12];
    const float* g2      = (const float*)d_in[13];
    const float* beta2   = (const float*)d_in[14];
    const float* W1      = (const float*)d_in[15];
    const float* b1      = (const float*)d_in[16];
    const float* W2      = (const float*)d_in[17];
    const float* b2      = (const float*)d_in[18];
    const float* Wc      = (const float*)d_in[19];
    const float* bc      = (const float*)d_in[20];
    float* outp = (float*)d_out;

    const int M  = BATCH * SEQ;           // 3152
    const int MP = BATCH * NPATCHES;      // 3136

    char* ws = (char*)d_ws;
    float* out  = (float*)ws; ws += (size_t)MPAD * 768 * 4;
    bf16*  xb   = (bf16*) ws; ws += (size_t)MPAD * 768 * 2;
    float* qkv  = (float*)ws; ws += (size_t)MPAD * 2304 * 4;
    bf16*  h    = (bf16*) ws; ws += (size_t)MPAD * 3072 * 2;
    bf16*  wqkv = (bf16*) ws; ws += (size_t)2304 * 768 * 2;
    bf16*  w1b  = (bf16*) ws; ws += (size_t)3072 * 768 * 2;
    bf16*  w2b  = (bf16*) ws; ws += (size_t)768 * 3072 * 2;
    float* bqkv = (float*)ws; ws += 2304 * 4;
    bf16*  wmb  = (bf16*) ws; ws += (size_t)768 * 768 * 2;
    float* logits = (float*)ws; ws += (size_t)BATCH * NCLS * 4;
    // split-K partial buffer: 4 slices x 3152 x 768 fp32 = 38.7 MB
    float* part = (float*)ws; ws += (size_t)4 * M * 768 * 4;
    const bool can_split = ((size_t)(ws - (char*)d_ws) <= ws_size);
    // overlays inside h (unused until first MLP1)
    bf16*  patches = (bf16*)h;
    float* tokens  = (float*)((char*)h + (size_t)MPAD * 768 * 2);

    hipFuncSetAttribute((const void*)attn_mfma_kernel,
                        hipFuncAttributeMaxDynamicSharedMemorySize, ATTN_LDS);

    // --- patch embedding ---
    f2b_kernel<<<576, 256, 0, stream>>>(Wm, wmb, 768 * 768);
    int tot_p = MP * 768;
    patchify_kernel<<<(tot_p + 255) / 256, 256, 0, stream>>>(images, patches, tot_p);
    if (can_split) {
        mfma_gemm<64, true><<<dim3(768 / 128, (MP + 127) / 128, 4), 256, 0, stream>>>(
            (const ushort_t*)patches, (const ushort_t*)wmb, nullptr, part, nullptr,
            MP, 768, 768, 0);
        reduce4_kernel<<<1180, 256, 0, stream>>>(part, bm, tokens,
                                                 MP * 768, 768, 0, (size_t)MP * 768);
    } else {
        mfma_gemm<64, true><<<dim3(768 / 128, (MP + 127) / 128), 256, 0, stream>>>(
            (const ushort_t*)patches, (const ushort_t*)wmb, bm, tokens, nullptr,
            MP, 768, 768, 0);
    }
    int tot_a = M * 768;
    assemble_kernel<<<(tot_a + 255) / 256, 256, 0, stream>>>(tokens, cls_tok, pe, out, tot_a);

    const int MB = (M + 127) / 128;  // 25
    const int conv_blocks = (CONV_VECS + BIAS_VECS + 255) / 256;

    for (int l = 0; l < NLAYER; ++l) {
        convert_layer_kernel<<<conv_blocks, 256, 0, stream>>>(
            Wq + (size_t)l * 768 * 768, Wk + (size_t)l * 768 * 768,
            Wv + (size_t)l * 768 * 768, W1 + (size_t)l * NMLP * 768,
            W2 + (size_t)l * 768 * NMLP, bq + l * 768, bk + l * 768, bv + l * 768,
            wqkv, w1b, w2b, bqkv);

        ln_kernel<<<M, 256, 0, stream>>>(out, g1 + l * 768, beta1 + l * 768, xb);
        // QKV: 450 blocks -> BK=32 (co-resident blocks hide latency)
        mfma_gemm<32, false><<<dim3(2304 / 128, MB), 256, 0, stream>>>(
            (const ushort_t*)xb, (const ushort_t*)wqkv, bqkv, qkv, nullptr,
            M, 2304, 768, 0);
        attn_mfma_kernel<<<BATCH * NHEAD, 256, ATTN_LDS, stream>>>(qkv, out);
        ln_kernel<<<M, 256, 0, stream>>>(out, g2 + l * 768, beta2 + l * 768, xb);
        // MLP1: 600 blocks -> BK=32
        mfma_gemm<32, false><<<dim3(NMLP / 128, MB), 256, 0, stream>>>(
            (const ushort_t*)xb, (const ushort_t*)w1b, b1 + l * NMLP, nullptr, h,
            M, NMLP, 768, 1);
        // MLP2: deterministic split-K=4 -> 600 blocks (2.34/CU), 12 iters each
        if (can_split) {
            mfma_gemm<64, true><<<dim3(768 / 128, MB, 4), 256, 0, stream>>>(
                (const ushort_t*)h, (const ushort_t*)w2b, nullptr, part, nullptr,
                M, 768, NMLP, 2);
            reduce4_kernel<<<1184, 256, 0, stream>>>(part, b2 + l * 768, out,
                                                     M * 768, 768, 2, (size_t)M * 768);
        } else {
            mfma_gemm<64, true><<<dim3(768 / 128, MB), 256, 0, stream>>>(
                (const ushort_t*)h, (const ushort_t*)w2b, b2 + l * 768, out, nullptr,
                M, 768, NMLP, 2);
        }
    }

    cls_logits_kernel<<<dim3(4, BATCH), 256, 0, stream>>>(out, Wc, bc, logits);
    cls_softmax_kernel<<<BATCH, 256, 0, stream>>>(logits, outp);
}